// Round 1
// baseline (302.651 us; speedup 1.0000x reference)
//
#include <hip/hip_runtime.h>
#include <cstddef>

// Problem constants (all powers of two — index math is bit ops only).
#define B_    128
#define IN_   256
#define OUT_  256
#define HS_   512

// ---------------------------------------------------------------------------
// K1: hactiv[b,i] = tanh( inputs[b]·i2h_w[i] + i2h_b[i]
//                         + sum_j (w[i,j] + alpha[i,j]*hebb[b,i,j]) * hidden[b,j] )
// One wave per row i; 64 lanes cover j in two float4 chunks (coalesced 1 KiB
// per load instruction). hidden/inputs fragments are lane-constant -> kept in
// registers, no LDS at all. Grid = 8 chunks x 128 samples, b fastest so blocks
// sharing the same w/alpha rows are co-resident (L2 reuse).
// ---------------------------------------------------------------------------
__global__ __launch_bounds__(256) void k1_hactiv(
    const float* __restrict__ inputs,   // [B, IN]
    const float* __restrict__ hidden,   // [B, HS]
    const float* __restrict__ hebb,     // [B, HS, HS]
    const float* __restrict__ i2h_w,    // [HS, IN]
    const float* __restrict__ i2h_b,    // [HS]
    const float* __restrict__ w,        // [HS, HS]
    const float* __restrict__ alpha,    // [HS, HS]
    float* __restrict__ hactiv)         // [B, HS]
{
    const int b     = blockIdx.x & (B_ - 1);
    const int chunk = blockIdx.x >> 7;        // 0..7, 64 rows each
    const int tid   = threadIdx.x;
    const int wave  = tid >> 6;               // 0..3
    const int lane  = tid & 63;

    // Lane-fixed operands (independent of row i): keep in registers.
    const float4* hid4 = (const float4*)(hidden + (size_t)b * HS_);
    const float4  h0   = hid4[lane];          // hidden[b, 4*lane .. 4*lane+3]
    const float4  h1   = hid4[lane + 64];     // hidden[b, 256+4*lane ..]
    const float4  in4  = ((const float4*)(inputs + (size_t)b * IN_))[lane];

    const int i0 = chunk * 64 + wave * 16;    // 16 rows per wave

    for (int r = 0; r < 16; ++r) {
        const int i = i0 + r;
        const float4* hb = (const float4*)(hebb + ((size_t)b * HS_ + i) * HS_);
        const float4* wr = (const float4*)(w     + (size_t)i * HS_);
        const float4* ar = (const float4*)(alpha + (size_t)i * HS_);

        const float4 hb0 = hb[lane];
        const float4 hb1 = hb[lane + 64];
        const float4 wv0 = wr[lane];
        const float4 wv1 = wr[lane + 64];
        const float4 av0 = ar[lane];
        const float4 av1 = ar[lane + 64];
        const float4 iw  = ((const float4*)(i2h_w + (size_t)i * IN_))[lane];

        float acc;
        acc  = (wv0.x + av0.x * hb0.x) * h0.x;
        acc += (wv0.y + av0.y * hb0.y) * h0.y;
        acc += (wv0.z + av0.z * hb0.z) * h0.z;
        acc += (wv0.w + av0.w * hb0.w) * h0.w;
        acc += (wv1.x + av1.x * hb1.x) * h1.x;
        acc += (wv1.y + av1.y * hb1.y) * h1.y;
        acc += (wv1.z + av1.z * hb1.z) * h1.z;
        acc += (wv1.w + av1.w * hb1.w) * h1.w;
        acc += iw.x * in4.x + iw.y * in4.y + iw.z * in4.z + iw.w * in4.w;

        // wave-wide (64-lane) sum
        #pragma unroll
        for (int off = 32; off > 0; off >>= 1)
            acc += __shfl_down(acc, off, 64);

        if (lane == 0)
            hactiv[(size_t)b * HS_ + i] = tanhf(acc + i2h_b[i]);
    }
}

// ---------------------------------------------------------------------------
// K2: heads. One block per sample b.
//   activout[b,o] = hactiv[b]·h2o_w[o] + h2o_b[o]   (thread o, OUT_=256)
//   valueout[b]   = hactiv[b]·h2v_w + h2v_b
//   da[b]         = tanh(hactiv[b]·h2da_w + h2da_b)
// ---------------------------------------------------------------------------
__global__ __launch_bounds__(256) void k2_heads(
    const float* __restrict__ hactiv,   // [B, HS]
    const float* __restrict__ h2o_w,    // [OUT, HS]
    const float* __restrict__ h2o_b,    // [OUT]
    const float* __restrict__ h2v_w,    // [HS]
    const float* __restrict__ h2v_b,    // [1]
    const float* __restrict__ h2da_w,   // [HS]
    const float* __restrict__ h2da_b,   // [1]
    float* __restrict__ activout,       // [B, OUT]
    float* __restrict__ valueout,       // [B]
    float* __restrict__ da)             // [B] (workspace)
{
    const int b   = blockIdx.x;
    const int tid = threadIdx.x;

    __shared__ float s_h[HS_];
    __shared__ float red_v[256];
    __shared__ float red_d[256];

    for (int t = tid; t < HS_; t += 256)
        s_h[t] = hactiv[(size_t)b * HS_ + t];
    __syncthreads();

    // activout: one output column per thread; s_h reads are broadcasts (free).
    const float4* wr  = (const float4*)(h2o_w + (size_t)tid * HS_);
    const float4* sh4 = (const float4*)s_h;
    float acc = 0.f;
    #pragma unroll 4
    for (int q = 0; q < HS_ / 4; ++q) {
        const float4 wv = wr[q];
        const float4 hv = sh4[q];
        acc += wv.x * hv.x + wv.y * hv.y + wv.z * hv.z + wv.w * hv.w;
    }
    activout[(size_t)b * OUT_ + tid] = acc + h2o_b[tid];

    // value / da dot products: block reduction.
    float pv = 0.f, pd = 0.f;
    for (int t = tid; t < HS_; t += 256) {
        const float hv = s_h[t];
        pv += hv * h2v_w[t];
        pd += hv * h2da_w[t];
    }
    red_v[tid] = pv;
    red_d[tid] = pd;
    __syncthreads();
    for (int s = 128; s > 0; s >>= 1) {
        if (tid < s) {
            red_v[tid] += red_v[tid + s];
            red_d[tid] += red_d[tid + s];
        }
        __syncthreads();
    }
    if (tid == 0) {
        valueout[b] = red_v[0] + h2v_b[0];
        da[b]       = tanhf(red_d[0] + h2da_b[0]);
    }
}

// ---------------------------------------------------------------------------
// K3: hebb_new = clip(hebb + da[b] * hactiv[b,i] * hidden[b,j], -1, 1)
// Pure streaming: float4 in, float4 out. Each block covers 8 full rows
// (8 * 128 float4 = 1024 = 256 threads * 4), so a block never crosses a
// sample boundary (512 rows per sample, 8 | 512).
// ---------------------------------------------------------------------------
__global__ __launch_bounds__(256) void k3_hebb(
    const float* __restrict__ hebb,     // [B, HS, HS]
    const float* __restrict__ hidden,   // [B, HS]
    const float* __restrict__ hactiv,   // [B, HS]
    const float* __restrict__ da,       // [B]
    float* __restrict__ hebb_new)       // [B, HS, HS]
{
    const int tid = threadIdx.x;
    const size_t base = (size_t)blockIdx.x * 1024;  // float4 index

    #pragma unroll
    for (int k = 0; k < 4; ++k) {
        const size_t idx = base + (size_t)k * 256 + tid;
        const int j4  = (int)(idx & 127);           // float4 col within row
        const int row = (int)(idx >> 7);            // b*HS + i
        const int i   = row & (HS_ - 1);
        const int b   = row >> 9;

        const float scale = da[b] * hactiv[(size_t)b * HS_ + i];
        const float4 hv = ((const float4*)hebb)[idx];
        const float4 hd = ((const float4*)hidden)[(size_t)b * (HS_ / 4) + j4];

        float4 r;
        r.x = fminf(fmaxf(fmaf(scale, hd.x, hv.x), -1.f), 1.f);
        r.y = fminf(fmaxf(fmaf(scale, hd.y, hv.y), -1.f), 1.f);
        r.z = fminf(fmaxf(fmaf(scale, hd.z, hv.z), -1.f), 1.f);
        r.w = fminf(fmaxf(fmaf(scale, hd.w, hv.w), -1.f), 1.f);
        ((float4*)hebb_new)[idx] = r;
    }
}

// ---------------------------------------------------------------------------
extern "C" void kernel_launch(void* const* d_in, const int* in_sizes, int n_in,
                              void* d_out, int out_size, void* d_ws, size_t ws_size,
                              hipStream_t stream)
{
    const float* inputs = (const float*)d_in[0];
    const float* hidden = (const float*)d_in[1];
    const float* hebb   = (const float*)d_in[2];
    const float* i2h_w  = (const float*)d_in[3];
    const float* i2h_b  = (const float*)d_in[4];
    const float* w      = (const float*)d_in[5];
    const float* alpha  = (const float*)d_in[6];
    const float* h2o_w  = (const float*)d_in[7];
    const float* h2o_b  = (const float*)d_in[8];
    const float* h2v_w  = (const float*)d_in[9];
    const float* h2v_b  = (const float*)d_in[10];
    const float* h2da_w = (const float*)d_in[11];
    const float* h2da_b = (const float*)d_in[12];

    float* out = (float*)d_out;
    // Output layout (flat, return order): activout | valueout | hactiv | hebb_new
    float* activout = out;                              // 128*256   = 32768
    float* valueout = out + 32768;                      // 128
    float* hactiv   = out + 32768 + 128;                // 128*512   = 65536
    float* hebb_new = out + 32768 + 128 + 65536;        // 128*512*512

    float* da = (float*)d_ws;                           // [128] scratch

    // K1: 8 row-chunks x 128 samples (b fastest for w/alpha L2 reuse)
    k1_hactiv<<<dim3(1024), dim3(256), 0, stream>>>(
        inputs, hidden, hebb, i2h_w, i2h_b, w, alpha, hactiv);

    // K2: one block per sample
    k2_heads<<<dim3(B_), dim3(256), 0, stream>>>(
        hactiv, h2o_w, h2o_b, h2v_w, h2v_b, h2da_w, h2da_b,
        activout, valueout, da);

    // K3: 65536 rows / 8 rows per block = 8192 blocks
    k3_hebb<<<dim3(8192), dim3(256), 0, stream>>>(
        hebb, hidden, hactiv, da, hebb_new);
}